// Round 6
// baseline (61.832 us; speedup 1.0000x reference)
//
#include <hip/hip_runtime.h>
#include <stdint.h>

// FusedFP4Linear: out = gelu(x @ dequant(w_fp4)^T + bias)
// M=128, K=4096, N=16384. Weights [N, K/2] int32, low byte = two FP4 nibbles
// (hi nibble = even k, lo nibble = odd k).
// R6: weight-compaction prepass (134 MB int32 -> 33.5 MB bytes in ws);
// GEMM B-load = 1 dword/thread/tile (2 KB/tile vs 8 KB). Pipeline identical
// to R5 (BN=64, 8 waves, NBUF=4, counted vmcnt, decode-once-at-staging).

#define M_DIM 128
#define K_DIM 4096
#define N_DIM 16384
#define KP    (K_DIM/2)        // 2048 ints (or compact bytes) per weight row
#define BN    64
#define BK    64
#define NK    (K_DIM/BK)       // 64
#define NT    512              // 8 waves
#define NBLK  (N_DIM/BN)       // 256

#define A_BYTES 16384          // 128 rows x 128B bf16
#define B_BYTES 8192           // 64 rows x 128B bf16 (decoded)
#define NBUF    4
#define AOFF(b) ((b)*A_BYTES)
#define BOFF(b) (NBUF*A_BYTES + (b)*B_BYTES)
#define LDS_SZ  (NBUF*(A_BYTES+B_BYTES))   // 98304

#define XB_BYTES  ((size_t)M_DIM * K_DIM * 2)   // 1 MB
#define WPK_BYTES ((size_t)N_DIM * KP)          // 33.5 MB

typedef __attribute__((ext_vector_type(8))) __bf16 bf16x8;
typedef __attribute__((ext_vector_type(4))) float  f32x4;
typedef unsigned short ushort_t;

__device__ __forceinline__ unsigned f2b_bits(float f) {
  unsigned u = __builtin_bit_cast(unsigned, f);
  u += 0x7FFFu + ((u >> 16) & 1u);   // RNE
  return u >> 16;
}

__global__ __launch_bounds__(256) void convert_x_kernel(
    const float* __restrict__ x, ushort_t* __restrict__ xb) {
  int i = (blockIdx.x * blockDim.x + threadIdx.x) * 4;
  float4 v = *(const float4*)(x + i);
  ushort4 p;
  p.x = (ushort_t)f2b_bits(v.x);
  p.y = (ushort_t)f2b_bits(v.y);
  p.z = (ushort_t)f2b_bits(v.z);
  p.w = (ushort_t)f2b_bits(v.w);
  *(ushort4*)(xb + i) = p;
}

// low bytes of 4 ints -> 4 packed bytes
__device__ __forceinline__ unsigned pack4(uint4 p) {
  unsigned u01 = __builtin_amdgcn_perm(p.y, p.x, 0x04000400u);  // [x0,y0,x0,y0]
  unsigned u23 = __builtin_amdgcn_perm(p.w, p.z, 0x04000400u);
  return __builtin_amdgcn_perm(u23, u01, 0x05040100u);          // [x0,y0,z0,w0]
}

__global__ __launch_bounds__(256) void compact_w_kernel(
    const int* __restrict__ wq, uint8_t* __restrict__ wpk) {
  size_t idx = (size_t)blockIdx.x * 256 + threadIdx.x;  // 16 ints each
  const uint4* s = (const uint4*)wq + idx * 4;
  uint4 a = s[0], b = s[1], c = s[2], d = s[3];
  uint4 o;
  o.x = pack4(a); o.y = pack4(b); o.z = pack4(c); o.w = pack4(d);
  ((uint4*)wpk)[idx] = o;
}

__device__ __forceinline__ void gl16(const void* g, void* l) {
  __builtin_amdgcn_global_load_lds(
      (const __attribute__((address_space(1))) void*)g,
      (__attribute__((address_space(3))) void*)l, 16, 0, 0);
}

// 4 packed bytes (q) -> 8 bf16 (k-order: byte0.hi, byte0.lo, byte1.hi, ...)
__device__ __forceinline__ bf16x8 decode4(unsigned q) {
  unsigned e  = (q >> 4) & 0x0F0F0F0Fu;    // even-k nibbles
  unsigned o  = q & 0x0F0F0F0Fu;           // odd-k nibbles
  unsigned em = e & 0x07070707u, om = o & 0x07070707u;
  unsigned elo = __builtin_amdgcn_perm(0xC0804000u, 0xC0800000u, em);
  unsigned ehi = __builtin_amdgcn_perm(0x40404040u, 0x3F3F3F00u, em);
  unsigned olo = __builtin_amdgcn_perm(0xC0804000u, 0xC0800000u, om);
  unsigned ohi = __builtin_amdgcn_perm(0x40404040u, 0x3F3F3F00u, om);
  ehi |= (e & 0x08080808u) << 4;           // sign -> bit7 of high byte
  ohi |= (o & 0x08080808u) << 4;
  unsigned t0 = __builtin_amdgcn_perm(ehi, elo, 0x05010400u);
  unsigned t1 = __builtin_amdgcn_perm(ohi, olo, 0x05010400u);
  unsigned t2 = __builtin_amdgcn_perm(ehi, elo, 0x07030602u);
  unsigned t3 = __builtin_amdgcn_perm(ohi, olo, 0x07030602u);
  uint4 r;
  r.x = __builtin_amdgcn_perm(t1, t0, 0x05040100u);
  r.y = __builtin_amdgcn_perm(t1, t0, 0x07060302u);
  r.z = __builtin_amdgcn_perm(t3, t2, 0x05040100u);
  r.w = __builtin_amdgcn_perm(t3, t2, 0x07060302u);
  return __builtin_bit_cast(bf16x8, r);
}

// 4 packed int32 (low bytes) -> 8 bf16
__device__ __forceinline__ bf16x8 decode8(uint4 p) { return decode4(pack4(p)); }

#define MFMA16(a_, b_, c_) __builtin_amdgcn_mfma_f32_16x16x32_bf16(a_, b_, c_, 0, 0, 0)

// MODE: 2 = compact bytes (ws), 1 = packed int32 direct, 0 = fp32-x fallback
template<int MODE>
__global__ __launch_bounds__(NT) void fp4gemm_kernel(
    const void* __restrict__ xsrc,        // bf16 xb (ws) or fp32 x (MODE 0)
    const void* __restrict__ wsrc,        // compact bytes (MODE 2) or int32
    const float* __restrict__ scale,      // [N]
    const float* __restrict__ bias,       // [N]
    float* __restrict__ out) {            // [M, N]
  __shared__ __align__(16) uint8_t lds[LDS_SZ];

  const int t   = threadIdx.x;
  const int w   = t >> 6;                 // wave 0..7
  const int l   = t & 63;
  const int l16 = l & 15;
  const int lq  = l >> 4;
  const int mq  = w >> 1;                 // 0..3: rows mq*32..+31
  const int nh  = w & 1;                  // 0..1: cols nh*32..+31

  // XCD-aware bijective swizzle (256 % 8 == 0)
  const int bid = blockIdx.x;
  const int n0  = ((bid & 7) * (NBLK / 8) + (bid >> 3)) * BN;

  // staging geometry: 512 threads x 16B = 8KB = 64 rows x 128B
  const int srow = t >> 3;                // 0..63
  const int scol = (t & 7) * 16;          // byte col 0..112
  const int sswz = (srow & 7) << 4;
  const int scbs = scol ^ sswz;           // swizzled A-source col
  const int bwr  = srow * 128 + (scol ^ sswz);  // B LDS write offset

  const uint8_t* xb  = (const uint8_t*)xsrc;  // bf16 row = 8192 B
  const uint8_t* wqb = (const uint8_t*)wsrc;  // int32 row = 8192 B
  const uint8_t* wpk = (const uint8_t*)wsrc;  // compact row = 2048 B

  unsigned rs0, rs1, rs2, rs3;            // MODE 2: compact dword slots
  uint4    rq0, rq1, rq2, rq3;            // MODE 1: packed int4 slots

#define ISSUE_A(k_, b_) do { \
  gl16(xb + (size_t)(srow) * 8192 + (size_t)(k_) * 128 + scbs, \
       lds + AOFF(b_) + w * 1024); \
  gl16(xb + (size_t)(64 + srow) * 8192 + (size_t)(k_) * 128 + scbs, \
       lds + AOFF(b_) + 8192 + w * 1024); \
} while (0)

#define ISSUE_B(k_, s_) do { \
  if constexpr (MODE == 2) { \
    rs##s_ = *(const unsigned*)(wpk + (size_t)(n0 + srow) * KP + \
                                (size_t)(k_) * 32 + (t & 7) * 4); \
  } else { \
    rq##s_ = *(const uint4*)(wqb + (size_t)(n0 + srow) * 8192 + \
                             (size_t)(k_) * 128 + scol); \
  } \
} while (0)

#define DECODE_B(s_, b_) do { \
  bf16x8 dv_; \
  if constexpr (MODE == 2) dv_ = decode4(rs##s_); \
  else                     dv_ = decode8(rq##s_); \
  *(bf16x8*)(lds + BOFF(b_) + bwr) = dv_; \
} while (0)

#define WAITV(N_) asm volatile("s_waitcnt vmcnt(" #N_ ")" ::: "memory")
#define BARRIER() do { \
  asm volatile("s_waitcnt lgkmcnt(0)" ::: "memory"); \
  __builtin_amdgcn_s_barrier(); \
  __builtin_amdgcn_sched_barrier(0); \
} while (0)

  f32x4 acc00 = {0,0,0,0}, acc01 = {0,0,0,0};
  f32x4 acc10 = {0,0,0,0}, acc11 = {0,0,0,0};

  const int cBase = (lq << 4) ^ ((l16 & 7) << 4);
  const int aR0 = (mq * 32 + l16) * 128;       // +2048 for mi=1
  const int bR0 = (nh * 32 + l16) * 128;       // +2048 for ni=1

#define COMPUTE(b_) do { \
  const uint8_t* Ab_ = lds + AOFF(b_); \
  const uint8_t* Bb_ = lds + BOFF(b_); \
  _Pragma("unroll") \
  for (int ks_ = 0; ks_ < 2; ++ks_) { \
    const int cS_ = (ks_ << 6) ^ cBase; \
    bf16x8 a0_ = *(const bf16x8*)(Ab_ + aR0 + cS_); \
    bf16x8 a1_ = *(const bf16x8*)(Ab_ + aR0 + 2048 + cS_); \
    bf16x8 b0_ = *(const bf16x8*)(Bb_ + bR0 + cS_); \
    bf16x8 b1_ = *(const bf16x8*)(Bb_ + bR0 + 2048 + cS_); \
    acc00 = MFMA16(a0_, b0_, acc00); \
    acc01 = MFMA16(a0_, b1_, acc01); \
    acc10 = MFMA16(a1_, b0_, acc10); \
    acc11 = MFMA16(a1_, b1_, acc11); \
  } \
} while (0)

// BODY(k): computes tile k (buf k&3); issues A(k+2) -> buf u=(k+2)&3;
// decodes B(k+2) (slot u) -> LDS buf u; issues B(k+6) -> slot u.
#define BODY(k_, u_, cb_) do { \
  ISSUE_A((k_) + 2, u_); \
  WAITV(6); \
  BARRIER(); \
  DECODE_B(u_, u_); \
  ISSUE_B((k_) + 6, u_); \
  COMPUTE(cb_); \
} while (0)

  if constexpr (MODE >= 1) {
    // ---- prologue ----
    ISSUE_B(0, 0); ISSUE_B(1, 1); ISSUE_B(2, 2); ISSUE_B(3, 3);
    ISSUE_A(0, 0); ISSUE_A(1, 1);
    WAITV(4);                       // B0..B3 arrived
    DECODE_B(0, 0); DECODE_B(1, 1);
    ISSUE_B(4, 0); ISSUE_B(5, 1);
    // kt = 0
    ISSUE_A(2, 2); WAITV(6); BARRIER();
    DECODE_B(2, 2); ISSUE_B(6, 2); COMPUTE(0);
    // kt = 1
    ISSUE_A(3, 3); WAITV(7); BARRIER();
    DECODE_B(3, 3); ISSUE_B(7, 3); COMPUTE(1);
    // ---- main loop: kt = 2..57 ----
    for (int j = 0; j < 14; ++j) {
      const int kt = 2 + 4 * j;
      BODY(kt + 0, 0, 2);
      BODY(kt + 1, 1, 3);
      BODY(kt + 2, 2, 0);
      BODY(kt + 3, 3, 1);
    }
    // ---- tail ----
    ISSUE_A(60, 0); WAITV(6); BARRIER(); DECODE_B(0, 0); COMPUTE(2);  // kt=58
    ISSUE_A(61, 1); WAITV(5); BARRIER(); DECODE_B(1, 1); COMPUTE(3);  // kt=59
    ISSUE_A(62, 2); WAITV(4); BARRIER(); DECODE_B(2, 2); COMPUTE(0);  // kt=60
    ISSUE_A(63, 3); WAITV(4); BARRIER(); DECODE_B(3, 3); COMPUTE(1);  // kt=61
    WAITV(2); BARRIER(); COMPUTE(2);                                   // kt=62
    WAITV(0); BARRIER(); COMPUTE(3);                                   // kt=63
  } else {
    // fallback: simple 2-buffer __syncthreads pipeline, fp32 x inline
    for (int kt = 0; kt < NK; ++kt) {
      __syncthreads();
#pragma unroll
      for (int i = 0; i < 2; ++i) {
        const float* xf = (const float*)xsrc +
            (size_t)(i * 64 + srow) * K_DIM + (size_t)kt * BK + (scol >> 1);
        float4 v0 = *(const float4*)(xf);
        float4 v1 = *(const float4*)(xf + 4);
        uint4 pk = make_uint4(f2b_bits(v0.x) | (f2b_bits(v0.y) << 16),
                              f2b_bits(v0.z) | (f2b_bits(v0.w) << 16),
                              f2b_bits(v1.x) | (f2b_bits(v1.y) << 16),
                              f2b_bits(v1.z) | (f2b_bits(v1.w) << 16));
        *(uint4*)(lds + AOFF(kt & 1) + (size_t)(i * 64 + srow) * 128 +
                  (scol ^ sswz)) = pk;
      }
      {
        uint4 pv = *(const uint4*)(wqb + (size_t)(n0 + srow) * 8192 +
                                   (size_t)kt * 128 + scol);
        *(bf16x8*)(lds + BOFF(kt & 1) + bwr) = decode8(pv);
      }
      __syncthreads();
      COMPUTE(kt & 1);
    }
  }

  // ---- epilogue: scale, bias, exact GELU ----
  const int ng = n0 + nh * 32 + l16;
#pragma unroll
  for (int ni = 0; ni < 2; ++ni) {
    const int ngc = ng + ni * 16;
    const float s  = scale[ngc];
    const float bb = bias[ngc];
    f32x4 v0 = ni ? acc01 : acc00;
    f32x4 v1 = ni ? acc11 : acc10;
#pragma unroll
    for (int mi = 0; mi < 2; ++mi) {
      f32x4 vv = mi ? v1 : v0;
#pragma unroll
      for (int j = 0; j < 4; ++j) {
        int m = mq * 32 + mi * 16 + lq * 4 + j;
        float y = vv[j] * s + bb;
        float g = 0.5f * y * (1.0f + erff(y * 0.70710678118654752f));
        out[(size_t)m * N_DIM + ngc] = g;
      }
    }
  }
#undef ISSUE_A
#undef ISSUE_B
#undef DECODE_B
#undef WAITV
#undef BARRIER
#undef COMPUTE
#undef BODY
}

extern "C" void kernel_launch(void* const* d_in, const int* in_sizes, int n_in,
                              void* d_out, int out_size, void* d_ws, size_t ws_size,
                              hipStream_t stream) {
  const float* x     = (const float*)d_in[0];
  const int*   wq    = (const int*)d_in[1];
  const float* scale = (const float*)d_in[2];
  const float* bias  = (const float*)d_in[3];
  float* out = (float*)d_out;

  if (ws_size >= XB_BYTES + WPK_BYTES) {
    ushort_t* xb  = (ushort_t*)d_ws;
    uint8_t*  wpk = (uint8_t*)d_ws + XB_BYTES;
    convert_x_kernel<<<(M_DIM * K_DIM) / (256 * 4), 256, 0, stream>>>(x, xb);
    compact_w_kernel<<<(int)(WPK_BYTES / (256 * 16)), 256, 0, stream>>>(wq, wpk);
    fp4gemm_kernel<2><<<NBLK, NT, 0, stream>>>(xb, wpk, scale, bias, out);
  } else if (ws_size >= XB_BYTES) {
    ushort_t* xb = (ushort_t*)d_ws;
    convert_x_kernel<<<(M_DIM * K_DIM) / (256 * 4), 256, 0, stream>>>(x, xb);
    fp4gemm_kernel<1><<<NBLK, NT, 0, stream>>>(xb, wq, scale, bias, out);
  } else {
    fp4gemm_kernel<0><<<NBLK, NT, 0, stream>>>(x, wq, scale, bias, out);
  }
}

// Round 7
// 41.961 us; speedup vs baseline: 1.4736x; 1.4736x over previous
//
#include <hip/hip_runtime.h>
#include <stdint.h>

// FusedFP4Linear: out = gelu(x @ dequant(w_fp4)^T + bias)
// M=128, K=4096, N=16384. Weights [N, K/2] int32, low byte = two FP4 nibbles
// (hi nibble = even k, lo nibble = odd k).
// R7: k-split waves. 8 waves = 4 output positions (2m x 2n of 64x32) x 2
// k-halves; each wave computes a 32-wide k-slice per tile (6 ds_read_b128 +
// 8 MFMA, was 8 reads) -> per-CU LDS reads/tile 64 -> 48. Cross-wave acc
// reduce through LDS once at the end. A-prefetch depth 3 (NBUF=4), counted
// vmcnt schedule re-derived (steady outstanding 9, vmcnt(6)). No prepass
// (R6 regression reverted).

#define M_DIM 128
#define K_DIM 4096
#define N_DIM 16384
#define BN    64
#define BK    64
#define NK    (K_DIM/BK)       // 64
#define NT    512              // 8 waves
#define NBLK  (N_DIM/BN)       // 256

#define A_BYTES 16384          // 128 rows x 128B bf16
#define B_BYTES 8192           // 64 rows x 128B bf16 (decoded)
#define NBUF    4
#define AOFF(b) ((b)*A_BYTES)
#define BOFF(b) (NBUF*A_BYTES + (b)*B_BYTES)
#define LDS_SZ  (NBUF*(A_BYTES+B_BYTES))   // 98304

typedef __attribute__((ext_vector_type(8))) __bf16 bf16x8;
typedef __attribute__((ext_vector_type(4))) float  f32x4;
typedef unsigned short ushort_t;

__device__ __forceinline__ unsigned f2b_bits(float f) {
  unsigned u = __builtin_bit_cast(unsigned, f);
  u += 0x7FFFu + ((u >> 16) & 1u);   // RNE
  return u >> 16;
}

__global__ __launch_bounds__(256) void convert_x_kernel(
    const float* __restrict__ x, ushort_t* __restrict__ xb) {
  int i = (blockIdx.x * blockDim.x + threadIdx.x) * 4;
  float4 v = *(const float4*)(x + i);
  ushort4 p;
  p.x = (ushort_t)f2b_bits(v.x);
  p.y = (ushort_t)f2b_bits(v.y);
  p.z = (ushort_t)f2b_bits(v.z);
  p.w = (ushort_t)f2b_bits(v.w);
  *(ushort4*)(xb + i) = p;
}

__device__ __forceinline__ void gl16(const void* g, void* l) {
  __builtin_amdgcn_global_load_lds(
      (const __attribute__((address_space(1))) void*)g,
      (__attribute__((address_space(3))) void*)l, 16, 0, 0);
}

// 4 packed int32 (low bytes) -> 8 bf16 (k-order: b0.hi, b0.lo, b1.hi, ...)
__device__ __forceinline__ bf16x8 decode8(uint4 p) {
  unsigned u01 = __builtin_amdgcn_perm(p.y, p.x, 0x04000400u);
  unsigned u23 = __builtin_amdgcn_perm(p.w, p.z, 0x04000400u);
  unsigned q   = __builtin_amdgcn_perm(u23, u01, 0x05040100u);  // [x0,y0,z0,w0]
  unsigned e  = (q >> 4) & 0x0F0F0F0Fu;    // even-k nibbles
  unsigned o  = q & 0x0F0F0F0Fu;           // odd-k nibbles
  unsigned em = e & 0x07070707u, om = o & 0x07070707u;
  unsigned elo = __builtin_amdgcn_perm(0xC0804000u, 0xC0800000u, em);
  unsigned ehi = __builtin_amdgcn_perm(0x40404040u, 0x3F3F3F00u, em);
  unsigned olo = __builtin_amdgcn_perm(0xC0804000u, 0xC0800000u, om);
  unsigned ohi = __builtin_amdgcn_perm(0x40404040u, 0x3F3F3F00u, om);
  ehi |= (e & 0x08080808u) << 4;           // sign -> bit7 of high byte
  ohi |= (o & 0x08080808u) << 4;
  unsigned t0 = __builtin_amdgcn_perm(ehi, elo, 0x05010400u);
  unsigned t1 = __builtin_amdgcn_perm(ohi, olo, 0x05010400u);
  unsigned t2 = __builtin_amdgcn_perm(ehi, elo, 0x07030602u);
  unsigned t3 = __builtin_amdgcn_perm(ohi, olo, 0x07030602u);
  uint4 r;
  r.x = __builtin_amdgcn_perm(t1, t0, 0x05040100u);
  r.y = __builtin_amdgcn_perm(t1, t0, 0x07060302u);
  r.z = __builtin_amdgcn_perm(t3, t2, 0x05040100u);
  r.w = __builtin_amdgcn_perm(t3, t2, 0x07060302u);
  return __builtin_bit_cast(bf16x8, r);
}

#define MFMA16(a_, b_, c_) __builtin_amdgcn_mfma_f32_16x16x32_bf16(a_, b_, c_, 0, 0, 0)

template<bool USE_XB>
__global__ __launch_bounds__(NT) void fp4gemm_kernel(
    const void* __restrict__ xsrc,        // bf16 xb (ws) or fp32 x
    const int*  __restrict__ wq,          // [N, K/2] packed
    const float* __restrict__ scale,      // [N]
    const float* __restrict__ bias,       // [N]
    float* __restrict__ out) {            // [M, N]
  __shared__ __align__(16) uint8_t lds[LDS_SZ];

  const int t   = threadIdx.x;
  const int w   = t >> 6;                 // wave 0..7
  const int l   = t & 63;
  const int l16 = l & 15;
  const int lq  = l >> 4;
  const int kh  = w >> 2;                 // k-half 0..1 (ks slice)
  const int mh  = (w >> 1) & 1;           // m-half: rows mh*64..+63
  const int nh  = w & 1;                  // n-half: cols nh*32..+31

  // XCD-aware bijective swizzle (256 % 8 == 0)
  const int bid = blockIdx.x;
  const int n0  = ((bid & 7) * (NBLK / 8) + (bid >> 3)) * BN;

  // staging geometry: 512 threads x 16B = 8KB = 64 rows x 128B
  const int srow = t >> 3;                // 0..63
  const int scol = (t & 7) * 16;          // byte col 0..112
  const int sswz = (srow & 7) << 4;
  const int scbs = scol ^ sswz;           // swizzled source col (gl16 path)
  const int bwr  = srow * 128 + (scol ^ sswz);  // B LDS write offset

  const uint8_t* xb  = (const uint8_t*)xsrc;  // bf16 row = 8192 B
  const uint8_t* wqb = (const uint8_t*)wq;    // int32 row = 8192 B

  uint4 rq0, rq1, rq2, rq3;               // B packed reg slots

#define ISSUE_A(k_, b_) do { \
  gl16(xb + (size_t)(srow) * 8192 + (size_t)(k_) * 128 + scbs, \
       lds + AOFF(b_) + w * 1024); \
  gl16(xb + (size_t)(64 + srow) * 8192 + (size_t)(k_) * 128 + scbs, \
       lds + AOFF(b_) + 8192 + w * 1024); \
} while (0)

#define ISSUE_B(k_, s_) do { \
  rq##s_ = *(const uint4*)(wqb + (size_t)(n0 + srow) * 8192 + \
                           (size_t)(k_) * 128 + scol); \
} while (0)

#define DECODE_B(s_, b_) do { \
  *(bf16x8*)(lds + BOFF(b_) + bwr) = decode8(rq##s_); \
} while (0)

#define WAITV(N_) asm volatile("s_waitcnt vmcnt(" #N_ ")" ::: "memory")
#define BARRIER() do { \
  asm volatile("s_waitcnt lgkmcnt(0)" ::: "memory"); \
  __builtin_amdgcn_s_barrier(); \
  __builtin_amdgcn_sched_barrier(0); \
} while (0)

  f32x4 acc[4][2] = {{{0,0,0,0},{0,0,0,0}},{{0,0,0,0},{0,0,0,0}},
                     {{0,0,0,0},{0,0,0,0}},{{0,0,0,0},{0,0,0,0}}};

  // read-side col offset: k-base (lq*16 + kh*64) XOR row-swizzle
  const int cS  = ((lq << 4) + (kh << 6)) ^ ((l16 & 7) << 4);
  const int aR0 = (mh * 64 + l16) * 128;       // + r*2048
  const int bR0 = (nh * 32 + l16) * 128;       // + c*2048

#define COMPUTE(b_) do { \
  const uint8_t* Ab_ = lds + AOFF(b_); \
  const uint8_t* Bb_ = lds + BOFF(b_); \
  bf16x8 bf0_ = *(const bf16x8*)(Bb_ + bR0 + cS); \
  bf16x8 bf1_ = *(const bf16x8*)(Bb_ + bR0 + 2048 + cS); \
  _Pragma("unroll") \
  for (int r_ = 0; r_ < 4; ++r_) { \
    bf16x8 af_ = *(const bf16x8*)(Ab_ + aR0 + r_ * 2048 + cS); \
    acc[r_][0] = MFMA16(af_, bf0_, acc[r_][0]); \
    acc[r_][1] = MFMA16(af_, bf1_, acc[r_][1]); \
  } \
} while (0)

// BODY(k): wait A(k); barrier; decode B(k+2) -> LDS buf u=(k+2)&3;
// issue B(k+6) -> slot u; issue A(k+3) -> buf ab=(k+3)&3; compute tile k.
#define BODY(k_, u_, ab_, cb_) do { \
  WAITV(6); \
  BARRIER(); \
  DECODE_B(u_, u_); \
  ISSUE_B((k_) + 6, u_); \
  ISSUE_A((k_) + 3, ab_); \
  COMPUTE(cb_); \
} while (0)

  if constexpr (USE_XB) {
    // ---- prologue ----  (FIFO trace verified; steady outstanding = 9)
    ISSUE_B(0, 0); ISSUE_B(1, 1); ISSUE_B(2, 2); ISSUE_B(3, 3);
    ISSUE_A(0, 0); ISSUE_A(1, 1); ISSUE_A(2, 2);
    WAITV(6);                       // B0..B3 landed
    DECODE_B(0, 0); DECODE_B(1, 1);
    ISSUE_B(4, 0); ISSUE_B(5, 1);
    // kt = 0
    WAITV(6); BARRIER();
    DECODE_B(2, 2); ISSUE_B(6, 2); ISSUE_A(3, 3); COMPUTE(0);
    // kt = 1
    WAITV(6); BARRIER();
    DECODE_B(3, 3); ISSUE_B(7, 3); ISSUE_A(4, 0); COMPUTE(1);
    // ---- main loop: kt = 2..57 ----
    for (int j = 0; j < 14; ++j) {
      BODY(2 + 4 * j, 0, 1, 2);
      BODY(3 + 4 * j, 1, 2, 3);
      BODY(4 + 4 * j, 2, 3, 0);
      BODY(5 + 4 * j, 3, 0, 1);
    }
    // ---- tail ----
    WAITV(6); BARRIER(); DECODE_B(0, 0); ISSUE_A(61, 1); COMPUTE(2);  // kt=58
    WAITV(5); BARRIER(); DECODE_B(1, 1); ISSUE_A(62, 2); COMPUTE(3);  // kt=59
    WAITV(4); BARRIER(); DECODE_B(2, 2); ISSUE_A(63, 3); COMPUTE(0);  // kt=60
    WAITV(4); BARRIER(); DECODE_B(3, 3); COMPUTE(1);                  // kt=61
    WAITV(2); BARRIER(); COMPUTE(2);                                  // kt=62
    WAITV(0); BARRIER(); COMPUTE(3);                                  // kt=63
  } else {
    // fallback (ws too small): simple 2-buffer __syncthreads pipeline
    for (int kt = 0; kt < NK; ++kt) {
      __syncthreads();
#pragma unroll
      for (int i = 0; i < 2; ++i) {
        const float* xf = (const float*)xsrc +
            (size_t)(i * 64 + srow) * K_DIM + (size_t)kt * BK + (scol >> 1);
        float4 v0 = *(const float4*)(xf);
        float4 v1 = *(const float4*)(xf + 4);
        uint4 pk = make_uint4(f2b_bits(v0.x) | (f2b_bits(v0.y) << 16),
                              f2b_bits(v0.z) | (f2b_bits(v0.w) << 16),
                              f2b_bits(v1.x) | (f2b_bits(v1.y) << 16),
                              f2b_bits(v1.z) | (f2b_bits(v1.w) << 16));
        *(uint4*)(lds + AOFF(kt & 1) + (size_t)(i * 64 + srow) * 128 +
                  (scol ^ sswz)) = pk;
      }
      {
        uint4 pv = *(const uint4*)(wqb + (size_t)(n0 + srow) * 8192 +
                                   (size_t)kt * 128 + scol);
        *(bf16x8*)(lds + BOFF(kt & 1) + bwr) = decode8(pv);
      }
      __syncthreads();
      COMPUTE(kt & 1);
    }
  }

  // ---- cross-wave k-reduce (pairs w, w+4 share output position w&3) ----
  __syncthreads();                        // all LDS buffer reads done
  {
    uint8_t* red = lds;                   // 4 pos x 8KB = 32KB (reuse)
    const int pos = w & 3;
    if (w >= 4) {
#pragma unroll
      for (int r = 0; r < 4; ++r)
#pragma unroll
        for (int c = 0; c < 2; ++c)
          *(f32x4*)(red + pos * 8192 + (r * 2 + c) * 1024 + l * 16) = acc[r][c];
    }
    __syncthreads();
    if (w < 4) {
#pragma unroll
      for (int r = 0; r < 4; ++r)
#pragma unroll
        for (int c = 0; c < 2; ++c)
          acc[r][c] += *(const f32x4*)(red + pos * 8192 + (r * 2 + c) * 1024 + l * 16);

      // ---- epilogue: scale, bias, exact GELU ----
#pragma unroll
      for (int c = 0; c < 2; ++c) {
        const int ngc = n0 + nh * 32 + c * 16 + l16;
        const float s  = scale[ngc];
        const float bb = bias[ngc];
#pragma unroll
        for (int r = 0; r < 4; ++r) {
#pragma unroll
          for (int j = 0; j < 4; ++j) {
            int m = mh * 64 + r * 16 + lq * 4 + j;
            float y = acc[r][c][j] * s + bb;
            float g = 0.5f * y * (1.0f + erff(y * 0.70710678118654752f));
            out[(size_t)m * N_DIM + ngc] = g;
          }
        }
      }
    }
  }
#undef ISSUE_A
#undef ISSUE_B
#undef DECODE_B
#undef WAITV
#undef BARRIER
#undef COMPUTE
#undef BODY
}

extern "C" void kernel_launch(void* const* d_in, const int* in_sizes, int n_in,
                              void* d_out, int out_size, void* d_ws, size_t ws_size,
                              hipStream_t stream) {
  const float* x     = (const float*)d_in[0];
  const int*   wq    = (const int*)d_in[1];
  const float* scale = (const float*)d_in[2];
  const float* bias  = (const float*)d_in[3];
  float* out = (float*)d_out;

  const size_t xb_bytes = (size_t)M_DIM * K_DIM * 2;   // 1 MB
  if (ws_size >= xb_bytes) {
    ushort_t* xb = (ushort_t*)d_ws;
    convert_x_kernel<<<(M_DIM * K_DIM) / (256 * 4), 256, 0, stream>>>(x, xb);
    fp4gemm_kernel<true><<<NBLK, NT, 0, stream>>>(xb, wq, scale, bias, out);
  } else {
    fp4gemm_kernel<false><<<NBLK, NT, 0, stream>>>(x, wq, scale, bias, out);
  }
}